// Round 2
// baseline (948.199 us; speedup 1.0000x reference)
//
#include <hip/hip_runtime.h>

#define KD 192
#define H6 6

typedef __attribute__((ext_vector_type(8))) short bf16x8;
typedef __attribute__((ext_vector_type(4))) float f32x4;

__device__ __forceinline__ unsigned short f2bf(float f) {
  unsigned u = __float_as_uint(f);
  u += 0x7FFFu + ((u >> 16) & 1u);
  return (unsigned short)(u >> 16);
}

// bias[h][i][j] = rpb_table[rel_idx(i,j)*6 + h]
__global__ void bias_k(const float* __restrict__ tab, float* __restrict__ biasw) {
  int t = blockIdx.x * 256 + threadIdx.x;
  if (t >= H6 * 64 * 64) return;
  int h = t >> 12, rem = t & 4095, i = rem >> 6, j = rem & 63;
  int idx = ((i >> 3) - (j >> 3) + 7) * 15 + ((i & 7) - (j & 7) + 7);
  biasw[t] = tab[idx * H6 + h];
}

// Generic C = A @ W^T GEMM, 64x64 tile per 256-thread block, K=192 fully in LDS.
// MODE 0 (ENH) : d0 = bf16(resid + (*scale_p)*acc), [M][192] bf16
// MODE 1 (QKV) : scatter acc+bias to up to 3 dsts; slot idx = col/192;
//                per-slot scale s0..s2; trmask bit set => transposed [b][h][d][tok]
// MODE 2 (PROJ): fdst[mblk*winStride + tok*192 + c] = acc + bias[c]  (f32)
template <int AF32, int MODE>
__global__ __launch_bounds__(256) void gemm_k(
    const void* __restrict__ Av, const float* __restrict__ W,
    const float* __restrict__ bias, const float* __restrict__ resid,
    const float* __restrict__ scale_p,
    unsigned short* __restrict__ d0, unsigned short* __restrict__ d1,
    unsigned short* __restrict__ d2,
    float s0, float s1, float s2, int trmask,
    float* __restrict__ fdst, long winStride)
{
  __shared__ short Al[64][200];   // padded to 200 -> 2-way-max bank aliasing
  __shared__ short Wl[64][200];
  const int tid = threadIdx.x;
  const int nblk = blockIdx.x, mblk = blockIdx.y;  // x = col tile (fast) for A reuse in L2
  const int row = tid >> 2, cb = (tid & 3) * 48;

  if (AF32) {
    const float* A = (const float*)Av + ((long)mblk * 64 + row) * KD + cb;
#pragma unroll
    for (int j = 0; j < 12; ++j) {
      float4 v = *(const float4*)(A + 4 * j);
      ushort4 p;
      p.x = f2bf(v.x); p.y = f2bf(v.y); p.z = f2bf(v.z); p.w = f2bf(v.w);
      *(ushort4*)&Al[row][cb + 4 * j] = p;
    }
  } else {
    const unsigned short* A = (const unsigned short*)Av + ((long)mblk * 64 + row) * KD + cb;
#pragma unroll
    for (int j = 0; j < 6; ++j) {
      float4 v = *(const float4*)(A + 8 * j);
      *(float4*)&Al[row][cb + 8 * j] = v;
    }
  }
  {
    const float* Wp = W + ((long)nblk * 64 + row) * KD + cb;
#pragma unroll
    for (int j = 0; j < 12; ++j) {
      float4 v = *(const float4*)(Wp + 4 * j);
      ushort4 p;
      p.x = f2bf(v.x); p.y = f2bf(v.y); p.z = f2bf(v.z); p.w = f2bf(v.w);
      *(ushort4*)&Wl[row][cb + 4 * j] = p;
    }
  }
  __syncthreads();

  const int lane = tid & 63, wv = tid >> 6;
  const int qn = lane & 15, g = lane >> 4;
  const f32x4 zero = {0.f, 0.f, 0.f, 0.f};
  f32x4 acc[4];
#pragma unroll
  for (int nt = 0; nt < 4; ++nt) acc[nt] = zero;

#pragma unroll
  for (int ks = 0; ks < 6; ++ks) {
    bf16x8 a = *(const bf16x8*)&Al[16 * wv + qn][32 * ks + 8 * g];
#pragma unroll
    for (int nt = 0; nt < 4; ++nt) {
      bf16x8 bfr = *(const bf16x8*)&Wl[16 * nt + qn][32 * ks + 8 * g];
      acc[nt] = __builtin_amdgcn_mfma_f32_16x16x32_bf16(a, bfr, acc[nt], 0, 0, 0);
    }
  }

  const int mloc = 16 * wv + 4 * g;  // + r gives row within 64-row tile (D: row=4g+r)
  if constexpr (MODE == 0) {
    const float sc = *scale_p;
#pragma unroll
    for (int nt = 0; nt < 4; ++nt) {
      const int c = nblk * 64 + 16 * nt + qn;
#pragma unroll
      for (int r = 0; r < 4; ++r) {
        const long m = (long)mblk * 64 + mloc + r;
        d0[m * KD + c] = f2bf(resid[m * KD + c] + sc * acc[nt][r]);
      }
    }
  } else if constexpr (MODE == 1) {
#pragma unroll
    for (int nt = 0; nt < 4; ++nt) {
      const int cg = nblk * 64 + 16 * nt + qn;
      const int idx = cg / KD;
      const int cc = cg - idx * KD;
      const int h = cc >> 5, d = cc & 31;
      unsigned short* dst = (idx == 0) ? d0 : ((idx == 1) ? d1 : d2);
      const float sca = (idx == 0) ? s0 : ((idx == 1) ? s1 : s2);
      const float bv = bias[cg];
      const long bwh = (long)mblk * H6 + h;   // one window per mblk (64 rows)
      if (((trmask >> idx) & 1) == 0) {
#pragma unroll
        for (int r = 0; r < 4; ++r)
          dst[(bwh * 64 + (mloc + r)) * 32 + d] = f2bf((acc[nt][r] + bv) * sca);
      } else {  // transposed: [b][h][d][tok], 4 consecutive tok -> 8B store
        ushort4 p;
        p.x = f2bf((acc[nt][0] + bv) * sca);
        p.y = f2bf((acc[nt][1] + bv) * sca);
        p.z = f2bf((acc[nt][2] + bv) * sca);
        p.w = f2bf((acc[nt][3] + bv) * sca);
        *(ushort4*)&dst[(bwh * 32 + d) * 64 + mloc] = p;
      }
    }
  } else {
#pragma unroll
    for (int nt = 0; nt < 4; ++nt) {
      const int c = nblk * 64 + 16 * nt + qn;
      const float bv = bias[c];
#pragma unroll
      for (int r = 0; r < 4; ++r)
        fdst[(long)mblk * winStride + (long)(mloc + r) * KD + c] = acc[nt][r] + bv;
    }
  }
}

// row-softmax on S^T register layout: lane qn holds q-row 16*nt+qn; its 16
// k-values are k = 16*mt + 4*g + r; lanes qn, qn+16, qn+32, qn+48 complete the row.
__device__ __forceinline__ void softmax_rows(f32x4 (&S)[4][4]) {
#pragma unroll
  for (int nt = 0; nt < 4; ++nt) {
    float mx = -3.0e38f;
#pragma unroll
    for (int mt = 0; mt < 4; ++mt)
#pragma unroll
      for (int r = 0; r < 4; ++r) mx = fmaxf(mx, S[mt][nt][r]);
    mx = fmaxf(mx, __shfl_xor(mx, 16));
    mx = fmaxf(mx, __shfl_xor(mx, 32));
    float sm = 0.f;
#pragma unroll
    for (int mt = 0; mt < 4; ++mt)
#pragma unroll
      for (int r = 0; r < 4; ++r) {
        float p = __expf(S[mt][nt][r] - mx);
        S[mt][nt][r] = p;
        sm += p;
      }
    sm += __shfl_xor(sm, 16);
    sm += __shfl_xor(sm, 32);
    const float inv = 1.f / sm;
#pragma unroll
    for (int mt = 0; mt < 4; ++mt)
#pragma unroll
      for (int r = 0; r < 4; ++r) S[mt][nt][r] *= inv;
  }
}

// O = P @ V  computed as O^T = V^T @ P^T ; P (S^T layout, f32) -> bf16 LDS -> B-frags.
// vTp: [b][h][32][64] bf16 (already transposed). out: [M][192] bf16 at col h*32.
__device__ __forceinline__ void pv_store(
    const f32x4 (&P)[4][4], const unsigned short* __restrict__ vTp,
    unsigned short* __restrict__ outp, long base, int b, int h, int qn, int g,
    short (*dt_lds)[72])
{
#pragma unroll
  for (int mt = 0; mt < 4; ++mt)
#pragma unroll
    for (int nt = 0; nt < 4; ++nt) {
      ushort4 p;
      p.x = f2bf(P[mt][nt][0]); p.y = f2bf(P[mt][nt][1]);
      p.z = f2bf(P[mt][nt][2]); p.w = f2bf(P[mt][nt][3]);
      *(ushort4*)&dt_lds[16 * nt + qn][16 * mt + 4 * g] = p;
    }
  __syncthreads();
  const f32x4 zero = {0.f, 0.f, 0.f, 0.f};
  f32x4 oa[2][4];
#pragma unroll
  for (int i = 0; i < 2; ++i)
#pragma unroll
    for (int nt = 0; nt < 4; ++nt) oa[i][nt] = zero;
#pragma unroll
  for (int ks = 0; ks < 2; ++ks) {
    bf16x8 va0 = *(const bf16x8*)&vTp[base + (0 + qn) * 64 + 32 * ks + 8 * g];
    bf16x8 va1 = *(const bf16x8*)&vTp[base + (16 + qn) * 64 + 32 * ks + 8 * g];
#pragma unroll
    for (int nt = 0; nt < 4; ++nt) {
      bf16x8 pb = *(const bf16x8*)&dt_lds[16 * nt + qn][32 * ks + 8 * g];
      oa[0][nt] = __builtin_amdgcn_mfma_f32_16x16x32_bf16(va0, pb, oa[0][nt], 0, 0, 0);
      oa[1][nt] = __builtin_amdgcn_mfma_f32_16x16x32_bf16(va1, pb, oa[1][nt], 0, 0, 0);
    }
  }
#pragma unroll
  for (int mt2 = 0; mt2 < 2; ++mt2)
#pragma unroll
    for (int nt = 0; nt < 4; ++nt) {
      const int q = 16 * nt + qn;
      ushort4 p;
      p.x = f2bf(oa[mt2][nt][0]); p.y = f2bf(oa[mt2][nt][1]);
      p.z = f2bf(oa[mt2][nt][2]); p.w = f2bf(oa[mt2][nt][3]);
      *(ushort4*)&outp[((long)b * 64 + q) * KD + h * 32 + 16 * mt2 + 4 * g] = p;
    }
  __syncthreads();  // protect LDS for the next pv_store / call
}

// one differential attention: S^T = K@Q^T + bias^T (both paths), softmax,
// dt = at - lam*ar, dr = ar - lam*at, O_t = dt@v_t, O_r = dr@v_r
__device__ __forceinline__ void diff_attn_one(
    const unsigned short* __restrict__ qb, const unsigned short* __restrict__ kb,
    const unsigned short* __restrict__ vTb, long pstride,
    const float* __restrict__ bh, float lam,
    unsigned short* __restrict__ o_t, unsigned short* __restrict__ o_r,
    int b, int h, int qn, int g, short (*dt_lds)[72])
{
  const long base = ((long)b * H6 + h) * 2048;
  f32x4 st[4][4], sr[4][4];
#pragma unroll
  for (int mt = 0; mt < 4; ++mt)
#pragma unroll
    for (int nt = 0; nt < 4; ++nt) {
      // acc init = bias[q][k]: q = 16nt+qn, k = 16mt+4g+(0..3)
      f32x4 bv = *(const f32x4*)&bh[(16 * nt + qn) * 64 + 16 * mt + 4 * g];
      st[mt][nt] = bv;
      sr[mt][nt] = bv;
    }
  {
    bf16x8 ka[4], qv[4];
#pragma unroll
    for (int mt = 0; mt < 4; ++mt)
      ka[mt] = *(const bf16x8*)&kb[base + (16 * mt + qn) * 32 + 8 * g];
#pragma unroll
    for (int nt = 0; nt < 4; ++nt)
      qv[nt] = *(const bf16x8*)&qb[base + (16 * nt + qn) * 32 + 8 * g];
#pragma unroll
    for (int mt = 0; mt < 4; ++mt)
#pragma unroll
      for (int nt = 0; nt < 4; ++nt)
        st[mt][nt] = __builtin_amdgcn_mfma_f32_16x16x32_bf16(ka[mt], qv[nt], st[mt][nt], 0, 0, 0);
#pragma unroll
    for (int mt = 0; mt < 4; ++mt)
      ka[mt] = *(const bf16x8*)&kb[pstride + base + (16 * mt + qn) * 32 + 8 * g];
#pragma unroll
    for (int nt = 0; nt < 4; ++nt)
      qv[nt] = *(const bf16x8*)&qb[pstride + base + (16 * nt + qn) * 32 + 8 * g];
#pragma unroll
    for (int mt = 0; mt < 4; ++mt)
#pragma unroll
      for (int nt = 0; nt < 4; ++nt)
        sr[mt][nt] = __builtin_amdgcn_mfma_f32_16x16x32_bf16(ka[mt], qv[nt], sr[mt][nt], 0, 0, 0);
  }
  softmax_rows(st);
  softmax_rows(sr);
#pragma unroll
  for (int mt = 0; mt < 4; ++mt)
#pragma unroll
    for (int nt = 0; nt < 4; ++nt)
#pragma unroll
      for (int r = 0; r < 4; ++r) {
        float a = st[mt][nt][r], rr = sr[mt][nt][r];
        st[mt][nt][r] = a - lam * rr;
        sr[mt][nt][r] = rr - lam * a;
      }
  pv_store(st, vTb, o_t, base, b, h, qn, g, dt_lds);
  pv_store(sr, vTb + pstride, o_r, base, b, h, qn, g, dt_lds);
}

__global__ __launch_bounds__(64) void attn_k(
    const unsigned short* __restrict__ saq, const unsigned short* __restrict__ sak,
    const unsigned short* __restrict__ savT,
    const unsigned short* __restrict__ caq, const unsigned short* __restrict__ cak,
    const unsigned short* __restrict__ cavT,
    const float* __restrict__ biasw, const float* __restrict__ lsp,
    const float* __restrict__ lcp,
    unsigned short* __restrict__ o0, unsigned short* __restrict__ o1,
    unsigned short* __restrict__ o2, unsigned short* __restrict__ o3,
    long pstride)
{
  __shared__ short dt_lds[64][72];
  const int wh = blockIdx.x;
  const int b = wh / H6, h = wh - b * H6;
  const int lane = threadIdx.x;
  const int qn = lane & 15, g = lane >> 4;
  const float* bh = biasw + (long)h * 4096;
  float ls = 1.f / (1.f + __expf(-*lsp));
  ls = fminf(fmaxf(ls, 0.01f), 0.99f);
  float lc = 1.f / (1.f + __expf(-*lcp));
  lc = fminf(fmaxf(lc, 0.01f), 0.99f);
  diff_attn_one(saq, sak, savT, pstride, bh, ls, o0, o1, b, h, qn, g, dt_lds);
  diff_attn_one(caq, cak, cavT, pstride, bh, lc, o2, o3, b, h, qn, g, dt_lds);
}

extern "C" void kernel_launch(void* const* d_in, const int* in_sizes, int n_in,
                              void* d_out, int out_size, void* d_ws, size_t ws_size,
                              hipStream_t stream)
{
  const float* x         = (const float*)d_in[0];
  const float* y         = (const float*)d_in[1];
  const float* sa_qkv_w  = (const float*)d_in[2];
  const float* sa_qkv_b  = (const float*)d_in[3];
  const float* sa_ct_w   = (const float*)d_in[4];
  const float* sa_cr_w   = (const float*)d_in[5];
  const float* ca_q_w    = (const float*)d_in[6];
  const float* ca_q_b    = (const float*)d_in[7];
  const float* ca_kv_w   = (const float*)d_in[8];
  const float* ca_kv_b   = (const float*)d_in[9];
  const float* ca_ct_w   = (const float*)d_in[10];
  const float* ca_cr_w   = (const float*)d_in[11];
  const float* rpb       = (const float*)d_in[12];
  const float* proj_sa_w = (const float*)d_in[13];
  const float* proj_sa_b = (const float*)d_in[14];
  const float* proj_ca_w = (const float*)d_in[15];
  const float* proj_ca_b = (const float*)d_in[16];
  const float* lam_sa_p  = (const float*)d_in[17];
  const float* lam_ca_p  = (const float*)d_in[18];
  const float* sa_enh_p  = (const float*)d_in[19];
  const float* ca_enh_p  = (const float*)d_in[20];
  float* out = (float*)d_out;

  const int M = in_sizes[0] / KD;        // B*64 = 65536
  const int B = M / 64;                  // 1024
  const long pstride = (long)B * H6 * 2048;  // elements per path per tensor

  // workspace layout
  char* ws = (char*)d_ws;
  float* biasw = (float*)ws;
  long off = 98304;
  unsigned short* enh0 = (unsigned short*)(ws + off); off += (long)M * KD * 2;
  unsigned short* enh1 = (unsigned short*)(ws + off); off += (long)M * KD * 2;
  unsigned short* enh2 = (unsigned short*)(ws + off); off += (long)M * KD * 2;
  unsigned short* enh3 = (unsigned short*)(ws + off); off += (long)M * KD * 2;
  unsigned short* caq  = (unsigned short*)(ws + off); off += pstride * 4;
  unsigned short* cak  = (unsigned short*)(ws + off); off += pstride * 4;
  unsigned short* cavT = (unsigned short*)(ws + off); off += pstride * 4;
  // sa qkv staged in d_out (151MB <= 201MB), fully overwritten by proj at the end
  unsigned short* saq  = (unsigned short*)d_out;
  unsigned short* sak  = saq + 2 * pstride;
  unsigned short* savT = sak + 2 * pstride;

  const float SC = 0.17677669529663687f;  // 32^-0.5
  dim3 blk(256);

  bias_k<<<dim3((H6 * 4096 + 255) / 256), dim3(256), 0, stream>>>(rpb, biasw);

  dim3 ge(3, M / 64);
  gemm_k<1, 0><<<ge, blk, 0, stream>>>(y, sa_cr_w, nullptr, x, sa_enh_p, enh0, nullptr, nullptr, 0.f, 0.f, 0.f, 0, nullptr, 0);
  gemm_k<1, 0><<<ge, blk, 0, stream>>>(x, sa_ct_w, nullptr, y, sa_enh_p, enh1, nullptr, nullptr, 0.f, 0.f, 0.f, 0, nullptr, 0);
  gemm_k<1, 0><<<ge, blk, 0, stream>>>(y, ca_cr_w, nullptr, x, ca_enh_p, enh2, nullptr, nullptr, 0.f, 0.f, 0.f, 0, nullptr, 0);
  gemm_k<1, 0><<<ge, blk, 0, stream>>>(x, ca_ct_w, nullptr, y, ca_enh_p, enh3, nullptr, nullptr, 0.f, 0.f, 0.f, 0, nullptr, 0);

  dim3 g9(9, M / 64);
  gemm_k<0, 1><<<g9, blk, 0, stream>>>(enh0, sa_qkv_w, sa_qkv_b, nullptr, nullptr,
                                       saq, sak, savT, SC, 1.f, 1.f, 4, nullptr, 0);
  gemm_k<0, 1><<<g9, blk, 0, stream>>>(enh1, sa_qkv_w, sa_qkv_b, nullptr, nullptr,
                                       saq + pstride, sak + pstride, savT + pstride, SC, 1.f, 1.f, 4, nullptr, 0);

  dim3 g3(3, M / 64);
  gemm_k<0, 1><<<g3, blk, 0, stream>>>(enh2, ca_q_w, ca_q_b, nullptr, nullptr,
                                       caq, nullptr, nullptr, SC, 1.f, 1.f, 0, nullptr, 0);
  gemm_k<0, 1><<<g3, blk, 0, stream>>>(enh3, ca_q_w, ca_q_b, nullptr, nullptr,
                                       caq + pstride, nullptr, nullptr, SC, 1.f, 1.f, 0, nullptr, 0);

  dim3 g6(6, M / 64);
  gemm_k<0, 1><<<g6, blk, 0, stream>>>(enh2, ca_kv_w, ca_kv_b, nullptr, nullptr,
                                       cak, cavT, nullptr, 1.f, 1.f, 1.f, 2, nullptr, 0);
  gemm_k<0, 1><<<g6, blk, 0, stream>>>(enh3, ca_kv_w, ca_kv_b, nullptr, nullptr,
                                       cak + pstride, cavT + pstride, nullptr, 1.f, 1.f, 1.f, 2, nullptr, 0);

  attn_k<<<dim3(B * H6), dim3(64), 0, stream>>>(saq, sak, savT, caq, cak, cavT,
                                                biasw, lam_sa_p, lam_ca_p,
                                                enh0, enh1, enh2, enh3, pstride);

  gemm_k<0, 2><<<g3, blk, 0, stream>>>(enh0, proj_sa_w, proj_sa_b, nullptr, nullptr,
                                       nullptr, nullptr, nullptr, 0.f, 0.f, 0.f, 0,
                                       out, 12288);
  gemm_k<0, 2><<<g3, blk, 0, stream>>>(enh1, proj_sa_w, proj_sa_b, nullptr, nullptr,
                                       nullptr, nullptr, nullptr, 0.f, 0.f, 0.f, 0,
                                       out + (long)B * 12288, 12288);
  gemm_k<0, 2><<<g3, blk, 0, stream>>>(enh2, proj_ca_w, proj_ca_b, nullptr, nullptr,
                                       nullptr, nullptr, nullptr, 0.f, 0.f, 0.f, 0,
                                       out + (long)2 * B * 12288, 24576);
  gemm_k<0, 2><<<g3, blk, 0, stream>>>(enh3, proj_ca_w, proj_ca_b, nullptr, nullptr,
                                       nullptr, nullptr, nullptr, 0.f, 0.f, 0.f, 0,
                                       out + ((long)2 * B + 1) * 12288, 24576);
}

// Round 3
// 779.374 us; speedup vs baseline: 1.2166x; 1.2166x over previous
//
#include <hip/hip_runtime.h>

#define KD 192
#define H6 6

typedef __attribute__((ext_vector_type(8))) short bf16x8;
typedef __attribute__((ext_vector_type(4))) float f32x4;

__device__ __forceinline__ unsigned short f2bf(float f) {
  unsigned u = __float_as_uint(f);
  u += 0x7FFFu + ((u >> 16) & 1u);
  return (unsigned short)(u >> 16);
}

// ---------------- bias table ----------------
__global__ void bias_k(const float* __restrict__ tab, float* __restrict__ biasw) {
  int t = blockIdx.x * 256 + threadIdx.x;
  if (t >= H6 * 64 * 64) return;
  int h = t >> 12, rem = t & 4095, i = rem >> 6, j = rem & 63;
  int idx = ((i >> 3) - (j >> 3) + 7) * 15 + ((i & 7) - (j & 7) + 7);
  biasw[t] = tab[idx * H6 + h];
}

// ---------------- weight pre-conversion (f32 -> bf16), one dispatch ----------------
__global__ void convert_k(
    const float* __restrict__ sa_qkv_w, const float* __restrict__ sa_ct_w,
    const float* __restrict__ sa_cr_w, const float* __restrict__ ca_q_w,
    const float* __restrict__ ca_kv_w, const float* __restrict__ ca_ct_w,
    const float* __restrict__ ca_cr_w, const float* __restrict__ proj_sa_w,
    const float* __restrict__ proj_ca_w,
    const float* __restrict__ ca_q_b, const float* __restrict__ ca_kv_b,
    unsigned short* __restrict__ wqkv, unsigned short* __restrict__ wct_sa,
    unsigned short* __restrict__ wcr_sa, unsigned short* __restrict__ wca,
    unsigned short* __restrict__ wct_ca, unsigned short* __restrict__ wcr_ca,
    unsigned short* __restrict__ wpsa, unsigned short* __restrict__ wpca,
    float* __restrict__ bca)
{
  int t = blockIdx.x * 256 + threadIdx.x;
  if (t < 110592) {                 // weight conversion, float4 units
    int i = t << 2;
    const float* s; unsigned short* d;
    if (i < 110592)      { s = sa_qkv_w + i;            d = wqkv + i; }
    else if (i < 147456) { s = sa_ct_w + (i - 110592);  d = wct_sa + (i - 110592); }
    else if (i < 184320) { s = sa_cr_w + (i - 147456);  d = wcr_sa + (i - 147456); }
    else if (i < 221184) { s = ca_q_w + (i - 184320);   d = wca + (i - 184320); }
    else if (i < 294912) { s = ca_kv_w + (i - 221184);  d = wca + 36864 + (i - 221184); }
    else if (i < 331776) { s = ca_ct_w + (i - 294912);  d = wct_ca + (i - 294912); }
    else if (i < 368640) { s = ca_cr_w + (i - 331776);  d = wcr_ca + (i - 331776); }
    else if (i < 405504) { s = proj_sa_w + (i - 368640); d = wpsa + (i - 368640); }
    else                 { s = proj_ca_w + (i - 405504); d = wpca + (i - 405504); }
    float4 v = *(const float4*)s;
    ushort4 p;
    p.x = f2bf(v.x); p.y = f2bf(v.y); p.z = f2bf(v.z); p.w = f2bf(v.w);
    *(ushort4*)d = p;
  } else if (t < 110592 + 144) {    // combined CA bias (f32 copy)
    int i = (t - 110592) << 2;
    const float* s = (i < 192) ? (ca_q_b + i) : (ca_kv_b + (i - 192));
    *(float4*)(bca + i) = *(const float4*)s;
  }
}

// ---------------- fused enhance: 4 outputs, x/y staged once ----------------
__global__ __launch_bounds__(256) void enh_k(
    const float* __restrict__ x, const float* __restrict__ y,
    const unsigned short* __restrict__ wcr_sa, const unsigned short* __restrict__ wct_sa,
    const unsigned short* __restrict__ wcr_ca, const unsigned short* __restrict__ wct_ca,
    const float* __restrict__ sap, const float* __restrict__ cap,
    unsigned short* __restrict__ e0, unsigned short* __restrict__ e1,
    unsigned short* __restrict__ e2, unsigned short* __restrict__ e3)
{
  __shared__ short Xl[64][200], Yl[64][200], Wl[64][200];
  const int tid = threadIdx.x;
  const int nblk = blockIdx.x, mblk = blockIdx.y;
  const int row = tid >> 2, cb = (tid & 3) * 48;
  {
    const float* xp = x + ((long)mblk * 64 + row) * KD + cb;
    const float* yp = y + ((long)mblk * 64 + row) * KD + cb;
#pragma unroll
    for (int j = 0; j < 12; ++j) {
      float4 vx = *(const float4*)(xp + 4 * j);
      float4 vy = *(const float4*)(yp + 4 * j);
      ushort4 px, py;
      px.x = f2bf(vx.x); px.y = f2bf(vx.y); px.z = f2bf(vx.z); px.w = f2bf(vx.w);
      py.x = f2bf(vy.x); py.y = f2bf(vy.y); py.z = f2bf(vy.z); py.w = f2bf(vy.w);
      *(ushort4*)&Xl[row][cb + 4 * j] = px;
      *(ushort4*)&Yl[row][cb + 4 * j] = py;
    }
  }
  const unsigned short* Ws[4] = {wcr_sa, wct_sa, wcr_ca, wct_ca};
  unsigned short* Es[4] = {e0, e1, e2, e3};
  const float s_sa = *sap, s_ca = *cap;

  const int lane = tid & 63, wv = tid >> 6;
  const int qn = lane & 15, g = lane >> 4;
  const int mloc = 16 * wv + 4 * g;
  const f32x4 zero = {0.f, 0.f, 0.f, 0.f};

  for (int it = 0; it < 4; ++it) {
    {
      const unsigned short* Wp = Ws[it] + ((long)nblk * 64 + row) * KD + cb;
#pragma unroll
      for (int j = 0; j < 6; ++j)
        *(float4*)&Wl[row][cb + 8 * j] = *(const float4*)(Wp + 8 * j);
    }
    __syncthreads();
    short (*Aloc)[200] = (it & 1) ? Xl : Yl;
    f32x4 acc[4];
#pragma unroll
    for (int nt = 0; nt < 4; ++nt) acc[nt] = zero;
#pragma unroll
    for (int ks = 0; ks < 6; ++ks) {
      bf16x8 a = *(const bf16x8*)&Aloc[16 * wv + qn][32 * ks + 8 * g];
#pragma unroll
      for (int nt = 0; nt < 4; ++nt) {
        bf16x8 bfr = *(const bf16x8*)&Wl[16 * nt + qn][32 * ks + 8 * g];
        acc[nt] = __builtin_amdgcn_mfma_f32_16x16x32_bf16(a, bfr, acc[nt], 0, 0, 0);
      }
    }
    const float* resid = (it & 1) ? y : x;
    const float sc = (it < 2) ? s_sa : s_ca;
    unsigned short* dst = Es[it];
#pragma unroll
    for (int nt = 0; nt < 4; ++nt) {
      const int c = nblk * 64 + 16 * nt + qn;
#pragma unroll
      for (int r = 0; r < 4; ++r) {
        const long m = (long)mblk * 64 + mloc + r;
        dst[m * KD + c] = f2bf(resid[m * KD + c] + sc * acc[nt][r]);
      }
    }
    __syncthreads();
  }
}

// ---------------- qkv: 4 paths via grid.z (SA t/r, CA t/r) ----------------
struct QkvArgs {
  const unsigned short* A[4];
  const unsigned short* W[4];
  const float* bias[4];
  unsigned short* dq[4];
  unsigned short* dk[4];
  unsigned short* dv[4];
};

__global__ __launch_bounds__(256) void qkv_k(QkvArgs args, float SC)
{
  __shared__ short Al[64][200], Wl[64][200];
  const int tid = threadIdx.x;
  const int nblk = blockIdx.x, mblk = blockIdx.y, z = blockIdx.z;
  const int row = tid >> 2, cb = (tid & 3) * 48;
  {
    const unsigned short* A = args.A[z] + ((long)mblk * 64 + row) * KD + cb;
#pragma unroll
    for (int j = 0; j < 6; ++j)
      *(float4*)&Al[row][cb + 8 * j] = *(const float4*)(A + 8 * j);
    const unsigned short* Wp = args.W[z] + ((long)nblk * 64 + row) * KD + cb;
#pragma unroll
    for (int j = 0; j < 6; ++j)
      *(float4*)&Wl[row][cb + 8 * j] = *(const float4*)(Wp + 8 * j);
  }
  __syncthreads();

  const int lane = tid & 63, wv = tid >> 6;
  const int qn = lane & 15, g = lane >> 4;
  const f32x4 zero = {0.f, 0.f, 0.f, 0.f};
  f32x4 acc[4];
#pragma unroll
  for (int nt = 0; nt < 4; ++nt) acc[nt] = zero;
#pragma unroll
  for (int ks = 0; ks < 6; ++ks) {
    bf16x8 a = *(const bf16x8*)&Al[16 * wv + qn][32 * ks + 8 * g];
#pragma unroll
    for (int nt = 0; nt < 4; ++nt) {
      bf16x8 bfr = *(const bf16x8*)&Wl[16 * nt + qn][32 * ks + 8 * g];
      acc[nt] = __builtin_amdgcn_mfma_f32_16x16x32_bf16(a, bfr, acc[nt], 0, 0, 0);
    }
  }
  const int mloc = 16 * wv + 4 * g;
#pragma unroll
  for (int nt = 0; nt < 4; ++nt) {
    const int cg = nblk * 64 + 16 * nt + qn;
    const int idx = (cg >= 384) ? 2 : ((cg >= 192) ? 1 : 0);
    const int cc = cg - idx * KD;
    const int h = cc >> 5, d = cc & 31;
    const float bv = args.bias[z][cg];
    const float sca = (idx == 0) ? SC : 1.f;
    const long bwh = (long)mblk * H6 + h;
    if (idx < 2) {
      unsigned short* dst = idx ? args.dk[z] : args.dq[z];
#pragma unroll
      for (int r = 0; r < 4; ++r)
        dst[(bwh * 64 + (mloc + r)) * 32 + d] = f2bf((acc[nt][r] + bv) * sca);
    } else {  // v transposed: [b][h][d][tok]
      ushort4 p;
      p.x = f2bf(acc[nt][0] + bv);
      p.y = f2bf(acc[nt][1] + bv);
      p.z = f2bf(acc[nt][2] + bv);
      p.w = f2bf(acc[nt][3] + bv);
      *(ushort4*)&args.dv[z][(bwh * 32 + d) * 64 + mloc] = p;
    }
  }
}

// ---------------- proj: 4 outputs via grid.z ----------------
struct ProjArgs {
  const unsigned short* A[4];
  const unsigned short* W[4];
  const float* bias[4];
  float* o[4];
  long wstride[4];
};

__global__ __launch_bounds__(256) void proj_k(ProjArgs args)
{
  __shared__ short Al[64][200], Wl[64][200];
  const int tid = threadIdx.x;
  const int nblk = blockIdx.x, mblk = blockIdx.y, z = blockIdx.z;
  const int row = tid >> 2, cb = (tid & 3) * 48;
  {
    const unsigned short* A = args.A[z] + ((long)mblk * 64 + row) * KD + cb;
#pragma unroll
    for (int j = 0; j < 6; ++j)
      *(float4*)&Al[row][cb + 8 * j] = *(const float4*)(A + 8 * j);
    const unsigned short* Wp = args.W[z] + ((long)nblk * 64 + row) * KD + cb;
#pragma unroll
    for (int j = 0; j < 6; ++j)
      *(float4*)&Wl[row][cb + 8 * j] = *(const float4*)(Wp + 8 * j);
  }
  __syncthreads();

  const int lane = tid & 63, wv = tid >> 6;
  const int qn = lane & 15, g = lane >> 4;
  const f32x4 zero = {0.f, 0.f, 0.f, 0.f};
  f32x4 acc[4];
#pragma unroll
  for (int nt = 0; nt < 4; ++nt) acc[nt] = zero;
#pragma unroll
  for (int ks = 0; ks < 6; ++ks) {
    bf16x8 a = *(const bf16x8*)&Al[16 * wv + qn][32 * ks + 8 * g];
#pragma unroll
    for (int nt = 0; nt < 4; ++nt) {
      bf16x8 bfr = *(const bf16x8*)&Wl[16 * nt + qn][32 * ks + 8 * g];
      acc[nt] = __builtin_amdgcn_mfma_f32_16x16x32_bf16(a, bfr, acc[nt], 0, 0, 0);
    }
  }
  const int mloc = 16 * wv + 4 * g;
  float* fo = args.o[z] + (long)mblk * args.wstride[z];
#pragma unroll
  for (int nt = 0; nt < 4; ++nt) {
    const int c = nblk * 64 + 16 * nt + qn;
    const float bv = args.bias[z][c];
#pragma unroll
    for (int r = 0; r < 4; ++r)
      fo[(long)(mloc + r) * KD + c] = acc[nt][r] + bv;
  }
}

// ---------------- attention: 4 waves/block, each wave = 32 q-rows of one (b,h) ----------------
__device__ __forceinline__ void softmax_rows2(f32x4 (&S)[4][2]) {
#pragma unroll
  for (int nt = 0; nt < 2; ++nt) {
    float mx = -3.0e38f;
#pragma unroll
    for (int mt = 0; mt < 4; ++mt)
#pragma unroll
      for (int r = 0; r < 4; ++r) mx = fmaxf(mx, S[mt][nt][r]);
    mx = fmaxf(mx, __shfl_xor(mx, 16));
    mx = fmaxf(mx, __shfl_xor(mx, 32));
    float sm = 0.f;
#pragma unroll
    for (int mt = 0; mt < 4; ++mt)
#pragma unroll
      for (int r = 0; r < 4; ++r) {
        float p = __expf(S[mt][nt][r] - mx);
        S[mt][nt][r] = p;
        sm += p;
      }
    sm += __shfl_xor(sm, 16);
    sm += __shfl_xor(sm, 32);
    const float inv = 1.f / sm;
#pragma unroll
    for (int mt = 0; mt < 4; ++mt)
#pragma unroll
      for (int r = 0; r < 4; ++r) S[mt][nt][r] *= inv;
  }
}

__device__ __forceinline__ void diff_attn32(
    const unsigned short* __restrict__ qb, const unsigned short* __restrict__ kb,
    const unsigned short* __restrict__ vTb, long pstride,
    const float* __restrict__ bh, float lam,
    unsigned short* __restrict__ o_t, unsigned short* __restrict__ o_r,
    long base, int b, int h, int qoff, int qn, int g,
    short (*Pl)[32][72])
{
  f32x4 st[4][2], sr[4][2];
#pragma unroll
  for (int mt = 0; mt < 4; ++mt)
#pragma unroll
    for (int nt = 0; nt < 2; ++nt) {
      f32x4 bv = *(const f32x4*)&bh[(qoff + 16 * nt + qn) * 64 + 16 * mt + 4 * g];
      st[mt][nt] = bv;
      sr[mt][nt] = bv;
    }
  {
    bf16x8 ka[4], qv[2];
#pragma unroll
    for (int mt = 0; mt < 4; ++mt)
      ka[mt] = *(const bf16x8*)&kb[base + (16 * mt + qn) * 32 + 8 * g];
#pragma unroll
    for (int nt = 0; nt < 2; ++nt)
      qv[nt] = *(const bf16x8*)&qb[base + (qoff + 16 * nt + qn) * 32 + 8 * g];
#pragma unroll
    for (int mt = 0; mt < 4; ++mt)
#pragma unroll
      for (int nt = 0; nt < 2; ++nt)
        st[mt][nt] = __builtin_amdgcn_mfma_f32_16x16x32_bf16(ka[mt], qv[nt], st[mt][nt], 0, 0, 0);
#pragma unroll
    for (int mt = 0; mt < 4; ++mt)
      ka[mt] = *(const bf16x8*)&kb[pstride + base + (16 * mt + qn) * 32 + 8 * g];
#pragma unroll
    for (int nt = 0; nt < 2; ++nt)
      qv[nt] = *(const bf16x8*)&qb[pstride + base + (qoff + 16 * nt + qn) * 32 + 8 * g];
#pragma unroll
    for (int mt = 0; mt < 4; ++mt)
#pragma unroll
      for (int nt = 0; nt < 2; ++nt)
        sr[mt][nt] = __builtin_amdgcn_mfma_f32_16x16x32_bf16(ka[mt], qv[nt], sr[mt][nt], 0, 0, 0);
  }
  softmax_rows2(st);
  softmax_rows2(sr);
  // mix and stage both P matrices to per-wave LDS (W-layout rows=q, cols=k)
#pragma unroll
  for (int mt = 0; mt < 4; ++mt)
#pragma unroll
    for (int nt = 0; nt < 2; ++nt) {
      ushort4 pt, pr;
#pragma unroll
      for (int r = 0; r < 4; ++r) {
        float a = st[mt][nt][r], rr = sr[mt][nt][r];
        ((unsigned short*)&pt)[r] = f2bf(a - lam * rr);
        ((unsigned short*)&pr)[r] = f2bf(rr - lam * a);
      }
      *(ushort4*)&Pl[0][16 * nt + qn][16 * mt + 4 * g] = pt;
      *(ushort4*)&Pl[1][16 * nt + qn][16 * mt + 4 * g] = pr;
    }
  const f32x4 zero = {0.f, 0.f, 0.f, 0.f};
#pragma unroll
  for (int p = 0; p < 2; ++p) {
    const unsigned short* vv = p ? (vTb + pstride) : vTb;
    unsigned short* outp = p ? o_r : o_t;
    f32x4 oa[2][2];
#pragma unroll
    for (int i = 0; i < 2; ++i)
#pragma unroll
      for (int nt = 0; nt < 2; ++nt) oa[i][nt] = zero;
#pragma unroll
    for (int ks = 0; ks < 2; ++ks) {
      bf16x8 va0 = *(const bf16x8*)&vv[base + (0 + qn) * 64 + 32 * ks + 8 * g];
      bf16x8 va1 = *(const bf16x8*)&vv[base + (16 + qn) * 64 + 32 * ks + 8 * g];
#pragma unroll
      for (int nt = 0; nt < 2; ++nt) {
        bf16x8 pb = *(const bf16x8*)&Pl[p][16 * nt + qn][32 * ks + 8 * g];
        oa[0][nt] = __builtin_amdgcn_mfma_f32_16x16x32_bf16(va0, pb, oa[0][nt], 0, 0, 0);
        oa[1][nt] = __builtin_amdgcn_mfma_f32_16x16x32_bf16(va1, pb, oa[1][nt], 0, 0, 0);
      }
    }
#pragma unroll
    for (int d16 = 0; d16 < 2; ++d16)
#pragma unroll
      for (int nt = 0; nt < 2; ++nt) {
        const int q = qoff + 16 * nt + qn;
        ushort4 pk;
        pk.x = f2bf(oa[d16][nt][0]); pk.y = f2bf(oa[d16][nt][1]);
        pk.z = f2bf(oa[d16][nt][2]); pk.w = f2bf(oa[d16][nt][3]);
        *(ushort4*)&outp[((long)b * 64 + q) * KD + h * 32 + 16 * d16 + 4 * g] = pk;
      }
  }
}

__global__ __launch_bounds__(256) void attn_k(
    const unsigned short* __restrict__ saq, const unsigned short* __restrict__ sak,
    const unsigned short* __restrict__ savT,
    const unsigned short* __restrict__ caq, const unsigned short* __restrict__ cak,
    const unsigned short* __restrict__ cavT,
    const float* __restrict__ biasw, const float* __restrict__ lsp,
    const float* __restrict__ lcp,
    unsigned short* __restrict__ o0, unsigned short* __restrict__ o1,
    unsigned short* __restrict__ o2, unsigned short* __restrict__ o3,
    long pstride)
{
  __shared__ short Pl[4][2][32][72];   // [wave][path][q][k] — per-wave private, no barriers
  const int wv = threadIdx.x >> 6, lane = threadIdx.x & 63;
  const int qn = lane & 15, g = lane >> 4;
  const int qoff = (wv & 1) * 32;
  const int wh = blockIdx.x * 2 + (wv >> 1);
  const int b = wh / H6, h = wh - b * H6;
  const float* bh = biasw + (long)h * 4096;
  const long base = (long)wh * 2048;
  float ls = 1.f / (1.f + __expf(-*lsp));
  ls = fminf(fmaxf(ls, 0.01f), 0.99f);
  float lc = 1.f / (1.f + __expf(-*lcp));
  lc = fminf(fmaxf(lc, 0.01f), 0.99f);
  diff_attn32(saq, sak, savT, pstride, bh, ls, o0, o1, base, b, h, qoff, qn, g, Pl[wv]);
  diff_attn32(caq, cak, cavT, pstride, bh, lc, o2, o3, base, b, h, qoff, qn, g, Pl[wv]);
}

// ---------------- host ----------------
extern "C" void kernel_launch(void* const* d_in, const int* in_sizes, int n_in,
                              void* d_out, int out_size, void* d_ws, size_t ws_size,
                              hipStream_t stream)
{
  const float* x         = (const float*)d_in[0];
  const float* y         = (const float*)d_in[1];
  const float* sa_qkv_w  = (const float*)d_in[2];
  const float* sa_qkv_b  = (const float*)d_in[3];
  const float* sa_ct_w   = (const float*)d_in[4];
  const float* sa_cr_w   = (const float*)d_in[5];
  const float* ca_q_w    = (const float*)d_in[6];
  const float* ca_q_b    = (const float*)d_in[7];
  const float* ca_kv_w   = (const float*)d_in[8];
  const float* ca_kv_b   = (const float*)d_in[9];
  const float* ca_ct_w   = (const float*)d_in[10];
  const float* ca_cr_w   = (const float*)d_in[11];
  const float* rpb       = (const float*)d_in[12];
  const float* proj_sa_w = (const float*)d_in[13];
  const float* proj_sa_b = (const float*)d_in[14];
  const float* proj_ca_w = (const float*)d_in[15];
  const float* proj_ca_b = (const float*)d_in[16];
  const float* lam_sa_p  = (const float*)d_in[17];
  const float* lam_ca_p  = (const float*)d_in[18];
  const float* sa_enh_p  = (const float*)d_in[19];
  const float* ca_enh_p  = (const float*)d_in[20];
  float* out = (float*)d_out;

  const int M = in_sizes[0] / KD;            // 65536
  const int B = M / 64;                      // 1024
  const long pstride = (long)B * H6 * 2048;  // 12,582,912 elements

  char* ws = (char*)d_ws;
  float* biasw = (float*)ws;                               // 98304 B
  float* bca = (float*)(ws + 98304);                       // 2304 B
  unsigned short* wqkv   = (unsigned short*)(ws + 100864); // 221184 B
  unsigned short* wca    = (unsigned short*)(ws + 322048); // 221184 B
  unsigned short* wct_sa = (unsigned short*)(ws + 543232);
  unsigned short* wcr_sa = (unsigned short*)(ws + 616960);
  unsigned short* wct_ca = (unsigned short*)(ws + 690688);
  unsigned short* wcr_ca = (unsigned short*)(ws + 764416);
  unsigned short* wpsa   = (unsigned short*)(ws + 838144);
  unsigned short* wpca   = (unsigned short*)(ws + 911872);
  long off = 1048576;
  unsigned short* enh0 = (unsigned short*)(ws + off); off += (long)M * KD * 2;
  unsigned short* enh1 = (unsigned short*)(ws + off); off += (long)M * KD * 2;
  unsigned short* enh2 = (unsigned short*)(ws + off); off += (long)M * KD * 2;
  unsigned short* enh3 = (unsigned short*)(ws + off); off += (long)M * KD * 2;
  unsigned short* caq  = (unsigned short*)(ws + off); off += pstride * 4;
  unsigned short* cak  = (unsigned short*)(ws + off); off += pstride * 4;
  unsigned short* cavT = (unsigned short*)(ws + off); off += pstride * 4;
  unsigned short* saq  = (unsigned short*)d_out;   // SA qkv staged in d_out (151 MB)
  unsigned short* sak  = saq + 2 * pstride;
  unsigned short* savT = sak + 2 * pstride;

  const float SC = 0.17677669529663687f;  // 32^-0.5

  convert_k<<<dim3(433), dim3(256), 0, stream>>>(
      sa_qkv_w, sa_ct_w, sa_cr_w, ca_q_w, ca_kv_w, ca_ct_w, ca_cr_w,
      proj_sa_w, proj_ca_w, ca_q_b, ca_kv_b,
      wqkv, wct_sa, wcr_sa, wca, wct_ca, wcr_ca, wpsa, wpca, bca);
  bias_k<<<dim3(96), dim3(256), 0, stream>>>(rpb, biasw);

  enh_k<<<dim3(3, B), dim3(256), 0, stream>>>(x, y, wcr_sa, wct_sa, wcr_ca, wct_ca,
                                              sa_enh_p, ca_enh_p, enh0, enh1, enh2, enh3);

  QkvArgs qa;
  qa.A[0] = enh0; qa.A[1] = enh1; qa.A[2] = enh2; qa.A[3] = enh3;
  qa.W[0] = wqkv; qa.W[1] = wqkv; qa.W[2] = wca; qa.W[3] = wca;
  qa.bias[0] = sa_qkv_b; qa.bias[1] = sa_qkv_b; qa.bias[2] = bca; qa.bias[3] = bca;
  qa.dq[0] = saq;  qa.dq[1] = saq + pstride;  qa.dq[2] = caq;  qa.dq[3] = caq + pstride;
  qa.dk[0] = sak;  qa.dk[1] = sak + pstride;  qa.dk[2] = cak;  qa.dk[3] = cak + pstride;
  qa.dv[0] = savT; qa.dv[1] = savT + pstride; qa.dv[2] = cavT; qa.dv[3] = cavT + pstride;
  qkv_k<<<dim3(9, B, 4), dim3(256), 0, stream>>>(qa, SC);

  attn_k<<<dim3(B * H6 / 2), dim3(256), 0, stream>>>(saq, sak, savT, caq, cak, cavT,
                                                     biasw, lam_sa_p, lam_ca_p,
                                                     enh0, enh1, enh2, enh3, pstride);

  ProjArgs pa;
  pa.A[0] = enh0; pa.A[1] = enh1; pa.A[2] = enh2; pa.A[3] = enh3;
  pa.W[0] = wpsa; pa.W[1] = wpsa; pa.W[2] = wpca; pa.W[3] = wpca;
  pa.bias[0] = proj_sa_b; pa.bias[1] = proj_sa_b; pa.bias[2] = proj_ca_b; pa.bias[3] = proj_ca_b;
  pa.o[0] = out;                       pa.wstride[0] = 12288;
  pa.o[1] = out + (long)B * 12288;     pa.wstride[1] = 12288;
  pa.o[2] = out + (long)2 * B * 12288; pa.wstride[2] = 24576;
  pa.o[3] = out + (long)2 * B * 12288 + 12288; pa.wstride[3] = 24576;
  proj_k<<<dim3(3, B, 4), dim3(256), 0, stream>>>(pa);
}

// Round 6
// 665.628 us; speedup vs baseline: 1.4245x; 1.1709x over previous
//
#include <hip/hip_runtime.h>

#define KD 192
#define H6 6

typedef __attribute__((ext_vector_type(8))) short bf16x8;
typedef __attribute__((ext_vector_type(4))) float f32x4;

__device__ __forceinline__ unsigned short f2bf(float f) {
  unsigned u = __float_as_uint(f);
  u += 0x7FFFu + ((u >> 16) & 1u);
  return (unsigned short)(u >> 16);
}

// ---------------- bias table ----------------
__global__ void bias_k(const float* __restrict__ tab, float* __restrict__ biasw) {
  int t = blockIdx.x * 256 + threadIdx.x;
  if (t >= H6 * 64 * 64) return;
  int h = t >> 12, rem = t & 4095, i = rem >> 6, j = rem & 63;
  int idx = ((i >> 3) - (j >> 3) + 7) * 15 + ((i & 7) - (j & 7) + 7);
  biasw[t] = tab[idx * H6 + h];
}

// ---------------- weight pre-conversion (f32 -> bf16), one dispatch ----------------
__global__ void convert_k(
    const float* __restrict__ sa_qkv_w, const float* __restrict__ sa_ct_w,
    const float* __restrict__ sa_cr_w, const float* __restrict__ ca_q_w,
    const float* __restrict__ ca_kv_w, const float* __restrict__ ca_ct_w,
    const float* __restrict__ ca_cr_w, const float* __restrict__ proj_sa_w,
    const float* __restrict__ proj_ca_w,
    const float* __restrict__ ca_q_b, const float* __restrict__ ca_kv_b,
    unsigned short* __restrict__ wqkv, unsigned short* __restrict__ wct_sa,
    unsigned short* __restrict__ wcr_sa, unsigned short* __restrict__ wca,
    unsigned short* __restrict__ wct_ca, unsigned short* __restrict__ wcr_ca,
    unsigned short* __restrict__ wpsa, unsigned short* __restrict__ wpca,
    float* __restrict__ bca)
{
  int t = blockIdx.x * 256 + threadIdx.x;
  if (t < 110592) {                 // weight conversion, float4 units
    int i = t << 2;
    const float* s; unsigned short* d;
    if (i < 110592)      { s = sa_qkv_w + i;            d = wqkv + i; }
    else if (i < 147456) { s = sa_ct_w + (i - 110592);  d = wct_sa + (i - 110592); }
    else if (i < 184320) { s = sa_cr_w + (i - 147456);  d = wcr_sa + (i - 147456); }
    else if (i < 221184) { s = ca_q_w + (i - 184320);   d = wca + (i - 184320); }
    else if (i < 294912) { s = ca_kv_w + (i - 221184);  d = wca + 36864 + (i - 221184); }
    else if (i < 331776) { s = ca_ct_w + (i - 294912);  d = wct_ca + (i - 294912); }
    else if (i < 368640) { s = ca_cr_w + (i - 331776);  d = wcr_ca + (i - 331776); }
    else if (i < 405504) { s = proj_sa_w + (i - 368640); d = wpsa + (i - 368640); }
    else                 { s = proj_ca_w + (i - 405504); d = wpca + (i - 405504); }
    float4 v = *(const float4*)s;
    ushort4 p;
    p.x = f2bf(v.x); p.y = f2bf(v.y); p.z = f2bf(v.z); p.w = f2bf(v.w);
    *(ushort4*)d = p;
  } else if (t < 110592 + 144) {    // combined CA bias (f32 copy)
    int i = (t - 110592) << 2;
    const float* s = (i < 192) ? (ca_q_b + i) : (ca_kv_b + (i - 192));
    *(float4*)(bca + i) = *(const float4*)s;
  }
}

// ---------------- fused enhance + qkv: one block = one (window, path) ----------------
// phase 1: stage A (x or y) f32->bf16 into LDS
// phase 2: 3 col-tiles of Wc -> enh = bf16(resid + sc*(A@Wc^T)) into LDS (never HBM)
// phase 3: 9 col-tiles of Wqkv -> scatter q/k/v (v transposed)
struct FQArgs {
  const unsigned short* Wc[4];
  const unsigned short* Wq[4];
  const float* bias[4];
  unsigned short* dq[4];
  unsigned short* dk[4];
  unsigned short* dv[4];
};

__global__ __launch_bounds__(256) void fqkv_k(
    const float* __restrict__ x, const float* __restrict__ y,
    const float* __restrict__ sap, const float* __restrict__ cap,
    FQArgs args, float SC)
{
  __shared__ short Al[64][200], Wl[64][200], El[64][200];
  const int tid = threadIdx.x;
  const int mblk = blockIdx.x, z = blockIdx.y;
  const int row = tid >> 2, cb = (tid & 3) * 48;
  const float* A    = (z & 1) ? x : y;
  const float* resd = (z & 1) ? y : x;
  const float sc = (z < 2) ? *sap : *cap;

  {  // phase 1
    const float* ap = A + ((long)mblk * 64 + row) * KD + cb;
#pragma unroll
    for (int j = 0; j < 12; ++j) {
      float4 v = *(const float4*)(ap + 4 * j);
      ushort4 p;
      p.x = f2bf(v.x); p.y = f2bf(v.y); p.z = f2bf(v.z); p.w = f2bf(v.w);
      *(ushort4*)&Al[row][cb + 4 * j] = p;
    }
  }
  const int lane = tid & 63, wv = tid >> 6;
  const int qn = lane & 15, g = lane >> 4;
  const int mloc = 16 * wv + 4 * g;
  const f32x4 zero = {0.f, 0.f, 0.f, 0.f};

  // phase 2: enh into El
  for (int ct = 0; ct < 3; ++ct) {
    {
      const unsigned short* Wp = args.Wc[z] + ((long)ct * 64 + row) * KD + cb;
#pragma unroll
      for (int j = 0; j < 6; ++j)
        *(float4*)&Wl[row][cb + 8 * j] = *(const float4*)(Wp + 8 * j);
    }
    __syncthreads();
    f32x4 acc[4];
#pragma unroll
    for (int nt = 0; nt < 4; ++nt) acc[nt] = zero;
#pragma unroll
    for (int ks = 0; ks < 6; ++ks) {
      bf16x8 a = *(const bf16x8*)&Al[16 * wv + qn][32 * ks + 8 * g];
#pragma unroll
      for (int nt = 0; nt < 4; ++nt) {
        bf16x8 bfr = *(const bf16x8*)&Wl[16 * nt + qn][32 * ks + 8 * g];
        acc[nt] = __builtin_amdgcn_mfma_f32_16x16x32_bf16(a, bfr, acc[nt], 0, 0, 0);
      }
    }
#pragma unroll
    for (int nt = 0; nt < 4; ++nt) {
      const int c = ct * 64 + 16 * nt + qn;
#pragma unroll
      for (int r = 0; r < 4; ++r)
        El[mloc + r][c] =
            f2bf(resd[((long)mblk * 64 + mloc + r) * KD + c] + sc * acc[nt][r]);
    }
    __syncthreads();
  }

  // phase 3: qkv from El
  for (int wt = 0; wt < 9; ++wt) {
    {
      const unsigned short* Wp = args.Wq[z] + ((long)wt * 64 + row) * KD + cb;
#pragma unroll
      for (int j = 0; j < 6; ++j)
        *(float4*)&Wl[row][cb + 8 * j] = *(const float4*)(Wp + 8 * j);
    }
    __syncthreads();
    f32x4 acc[4];
#pragma unroll
    for (int nt = 0; nt < 4; ++nt) acc[nt] = zero;
#pragma unroll
    for (int ks = 0; ks < 6; ++ks) {
      bf16x8 a = *(const bf16x8*)&El[16 * wv + qn][32 * ks + 8 * g];
#pragma unroll
      for (int nt = 0; nt < 4; ++nt) {
        bf16x8 bfr = *(const bf16x8*)&Wl[16 * nt + qn][32 * ks + 8 * g];
        acc[nt] = __builtin_amdgcn_mfma_f32_16x16x32_bf16(a, bfr, acc[nt], 0, 0, 0);
      }
    }
#pragma unroll
    for (int nt = 0; nt < 4; ++nt) {
      const int cg = wt * 64 + 16 * nt + qn;
      const int idx = (cg >= 384) ? 2 : ((cg >= 192) ? 1 : 0);
      const int cc = cg - idx * KD;
      const int h = cc >> 5, d = cc & 31;
      const float bv = args.bias[z][cg];
      const float sca = (idx == 0) ? SC : 1.f;
      const long bwh = (long)mblk * H6 + h;
      if (idx < 2) {
        unsigned short* dst = idx ? args.dk[z] : args.dq[z];
#pragma unroll
        for (int r = 0; r < 4; ++r)
          dst[(bwh * 64 + (mloc + r)) * 32 + d] = f2bf((acc[nt][r] + bv) * sca);
      } else {  // v transposed: [b][h][d][tok]
        ushort4 p;
        p.x = f2bf(acc[nt][0] + bv);
        p.y = f2bf(acc[nt][1] + bv);
        p.z = f2bf(acc[nt][2] + bv);
        p.w = f2bf(acc[nt][3] + bv);
        *(ushort4*)&args.dv[z][(bwh * 32 + d) * 64 + mloc] = p;
      }
    }
    __syncthreads();
  }
}

// ---------------- proj: stage A once, loop 3 W col-tiles; grid (B, 4) ----------------
struct ProjArgs {
  const unsigned short* A[4];
  const unsigned short* W[4];
  const float* bias[4];
  float* o[4];
  long wstride[4];
};

__global__ __launch_bounds__(256) void proj_k(ProjArgs args)
{
  __shared__ short Al[64][200], Wl[64][200];
  const int tid = threadIdx.x;
  const int mblk = blockIdx.x, z = blockIdx.y;
  const int row = tid >> 2, cb = (tid & 3) * 48;
  {
    const unsigned short* A = args.A[z] + ((long)mblk * 64 + row) * KD + cb;
#pragma unroll
    for (int j = 0; j < 6; ++j)
      *(float4*)&Al[row][cb + 8 * j] = *(const float4*)(A + 8 * j);
  }
  const int lane = tid & 63, wv = tid >> 6;
  const int qn = lane & 15, g = lane >> 4;
  const int mloc = 16 * wv + 4 * g;
  const f32x4 zero = {0.f, 0.f, 0.f, 0.f};
  float* fo = args.o[z] + (long)mblk * args.wstride[z];

  for (int ct = 0; ct < 3; ++ct) {
    {
      const unsigned short* Wp = args.W[z] + ((long)ct * 64 + row) * KD + cb;
#pragma unroll
      for (int j = 0; j < 6; ++j)
        *(float4*)&Wl[row][cb + 8 * j] = *(const float4*)(Wp + 8 * j);
    }
    __syncthreads();
    f32x4 acc[4];
#pragma unroll
    for (int nt = 0; nt < 4; ++nt) acc[nt] = zero;
#pragma unroll
    for (int ks = 0; ks < 6; ++ks) {
      bf16x8 a = *(const bf16x8*)&Al[16 * wv + qn][32 * ks + 8 * g];
#pragma unroll
      for (int nt = 0; nt < 4; ++nt) {
        bf16x8 bfr = *(const bf16x8*)&Wl[16 * nt + qn][32 * ks + 8 * g];
        acc[nt] = __builtin_amdgcn_mfma_f32_16x16x32_bf16(a, bfr, acc[nt], 0, 0, 0);
      }
    }
#pragma unroll
    for (int nt = 0; nt < 4; ++nt) {
      const int c = ct * 64 + 16 * nt + qn;
      const float bv = args.bias[z][c];
#pragma unroll
      for (int r = 0; r < 4; ++r)
        fo[(long)(mloc + r) * KD + c] = acc[nt][r] + bv;
    }
    __syncthreads();
  }
}

// ---------------- attention: 4 waves/block, each wave = 32 q-rows of one (b,h) ----------------
__device__ __forceinline__ void softmax_rows2(f32x4 (&S)[4][2]) {
#pragma unroll
  for (int nt = 0; nt < 2; ++nt) {
    float mx = -3.0e38f;
#pragma unroll
    for (int mt = 0; mt < 4; ++mt)
#pragma unroll
      for (int r = 0; r < 4; ++r) mx = fmaxf(mx, S[mt][nt][r]);
    mx = fmaxf(mx, __shfl_xor(mx, 16));
    mx = fmaxf(mx, __shfl_xor(mx, 32));
    float sm = 0.f;
#pragma unroll
    for (int mt = 0; mt < 4; ++mt)
#pragma unroll
      for (int r = 0; r < 4; ++r) {
        float p = __expf(S[mt][nt][r] - mx);
        S[mt][nt][r] = p;
        sm += p;
      }
    sm += __shfl_xor(sm, 16);
    sm += __shfl_xor(sm, 32);
    const float inv = 1.f / sm;
#pragma unroll
    for (int mt = 0; mt < 4; ++mt)
#pragma unroll
      for (int r = 0; r < 4; ++r) S[mt][nt][r] *= inv;
  }
}

__device__ __forceinline__ void diff_attn32(
    const unsigned short* __restrict__ qb, const unsigned short* __restrict__ kb,
    const unsigned short* __restrict__ vTb, long pstride,
    const float* __restrict__ bh, float lam,
    unsigned short* __restrict__ o_t, unsigned short* __restrict__ o_r,
    long base, int b, int h, int qoff, int qn, int g,
    short (*Pl)[32][72])
{
  f32x4 st[4][2], sr[4][2];
#pragma unroll
  for (int mt = 0; mt < 4; ++mt)
#pragma unroll
    for (int nt = 0; nt < 2; ++nt) {
      f32x4 bv = *(const f32x4*)&bh[(qoff + 16 * nt + qn) * 64 + 16 * mt + 4 * g];
      st[mt][nt] = bv;
      sr[mt][nt] = bv;
    }
  {
    bf16x8 ka[4], qv[2];
#pragma unroll
    for (int mt = 0; mt < 4; ++mt)
      ka[mt] = *(const bf16x8*)&kb[base + (16 * mt + qn) * 32 + 8 * g];
#pragma unroll
    for (int nt = 0; nt < 2; ++nt)
      qv[nt] = *(const bf16x8*)&qb[base + (qoff + 16 * nt + qn) * 32 + 8 * g];
#pragma unroll
    for (int mt = 0; mt < 4; ++mt)
#pragma unroll
      for (int nt = 0; nt < 2; ++nt)
        st[mt][nt] = __builtin_amdgcn_mfma_f32_16x16x32_bf16(ka[mt], qv[nt], st[mt][nt], 0, 0, 0);
#pragma unroll
    for (int mt = 0; mt < 4; ++mt)
      ka[mt] = *(const bf16x8*)&kb[pstride + base + (16 * mt + qn) * 32 + 8 * g];
#pragma unroll
    for (int nt = 0; nt < 2; ++nt)
      qv[nt] = *(const bf16x8*)&qb[pstride + base + (qoff + 16 * nt + qn) * 32 + 8 * g];
#pragma unroll
    for (int mt = 0; mt < 4; ++mt)
#pragma unroll
      for (int nt = 0; nt < 2; ++nt)
        sr[mt][nt] = __builtin_amdgcn_mfma_f32_16x16x32_bf16(ka[mt], qv[nt], sr[mt][nt], 0, 0, 0);
  }
  softmax_rows2(st);
  softmax_rows2(sr);
#pragma unroll
  for (int mt = 0; mt < 4; ++mt)
#pragma unroll
    for (int nt = 0; nt < 2; ++nt) {
      ushort4 pt, pr;
#pragma unroll
      for (int r = 0; r < 4; ++r) {
        float a = st[mt][nt][r], rr = sr[mt][nt][r];
        ((unsigned short*)&pt)[r] = f2bf(a - lam * rr);
        ((unsigned short*)&pr)[r] = f2bf(rr - lam * a);
      }
      *(ushort4*)&Pl[0][16 * nt + qn][16 * mt + 4 * g] = pt;
      *(ushort4*)&Pl[1][16 * nt + qn][16 * mt + 4 * g] = pr;
    }
  const f32x4 zero = {0.f, 0.f, 0.f, 0.f};
#pragma unroll
  for (int p = 0; p < 2; ++p) {
    const unsigned short* vv = p ? (vTb + pstride) : vTb;
    unsigned short* outp = p ? o_r : o_t;
    f32x4 oa[2][2];
#pragma unroll
    for (int i = 0; i < 2; ++i)
#pragma unroll
      for (int nt = 0; nt < 2; ++nt) oa[i][nt] = zero;
#pragma unroll
    for (int ks = 0; ks < 2; ++ks) {
      bf16x8 va0 = *(const bf16x8*)&vv[base + (0 + qn) * 64 + 32 * ks + 8 * g];
      bf16x8 va1 = *(const bf16x8*)&vv[base + (16 + qn) * 64 + 32 * ks + 8 * g];
#pragma unroll
      for (int nt = 0; nt < 2; ++nt) {
        bf16x8 pb = *(const bf16x8*)&Pl[p][16 * nt + qn][32 * ks + 8 * g];
        oa[0][nt] = __builtin_amdgcn_mfma_f32_16x16x32_bf16(va0, pb, oa[0][nt], 0, 0, 0);
        oa[1][nt] = __builtin_amdgcn_mfma_f32_16x16x32_bf16(va1, pb, oa[1][nt], 0, 0, 0);
      }
    }
#pragma unroll
    for (int d16 = 0; d16 < 2; ++d16)
#pragma unroll
      for (int nt = 0; nt < 2; ++nt) {
        const int q = qoff + 16 * nt + qn;
        ushort4 pk;
        pk.x = f2bf(oa[d16][nt][0]); pk.y = f2bf(oa[d16][nt][1]);
        pk.z = f2bf(oa[d16][nt][2]); pk.w = f2bf(oa[d16][nt][3]);
        *(ushort4*)&outp[((long)b * 64 + q) * KD + h * 32 + 16 * d16 + 4 * g] = pk;
      }
  }
}

__global__ __launch_bounds__(256) void attn_k(
    const unsigned short* __restrict__ saq, const unsigned short* __restrict__ sak,
    const unsigned short* __restrict__ savT,
    const unsigned short* __restrict__ caq, const unsigned short* __restrict__ cak,
    const unsigned short* __restrict__ cavT,
    const float* __restrict__ biasw, const float* __restrict__ lsp,
    const float* __restrict__ lcp,
    unsigned short* __restrict__ o0, unsigned short* __restrict__ o1,
    unsigned short* __restrict__ o2, unsigned short* __restrict__ o3,
    long pstride)
{
  __shared__ short Pl[4][2][32][72];   // [wave][path][q][k] — per-wave private, no barriers
  const int wv = threadIdx.x >> 6, lane = threadIdx.x & 63;
  const int qn = lane & 15, g = lane >> 4;
  const int qoff = (wv & 1) * 32;
  const int wh = blockIdx.x * 2 + (wv >> 1);
  const int b = wh / H6, h = wh - b * H6;
  const float* bh = biasw + (long)h * 4096;
  const long base = (long)wh * 2048;
  float ls = 1.f / (1.f + __expf(-*lsp));
  ls = fminf(fmaxf(ls, 0.01f), 0.99f);
  float lc = 1.f / (1.f + __expf(-*lcp));
  lc = fminf(fmaxf(lc, 0.01f), 0.99f);
  diff_attn32(saq, sak, savT, pstride, bh, ls, o0, o1, base, b, h, qoff, qn, g, Pl[wv]);
  diff_attn32(caq, cak, cavT, pstride, bh, lc, o2, o3, base, b, h, qoff, qn, g, Pl[wv]);
}

// ---------------- host ----------------
extern "C" void kernel_launch(void* const* d_in, const int* in_sizes, int n_in,
                              void* d_out, int out_size, void* d_ws, size_t ws_size,
                              hipStream_t stream)
{
  const float* x         = (const float*)d_in[0];
  const float* y         = (const float*)d_in[1];
  const float* sa_qkv_w  = (const float*)d_in[2];
  const float* sa_qkv_b  = (const float*)d_in[3];
  const float* sa_ct_w   = (const float*)d_in[4];
  const float* sa_cr_w   = (const float*)d_in[5];
  const float* ca_q_w    = (const float*)d_in[6];
  const float* ca_q_b    = (const float*)d_in[7];
  const float* ca_kv_w   = (const float*)d_in[8];
  const float* ca_kv_b   = (const float*)d_in[9];
  const float* ca_ct_w   = (const float*)d_in[10];
  const float* ca_cr_w   = (const float*)d_in[11];
  const float* rpb       = (const float*)d_in[12];
  const float* proj_sa_w = (const float*)d_in[13];
  const float* proj_sa_b = (const float*)d_in[14];
  const float* proj_ca_w = (const float*)d_in[15];
  const float* proj_ca_b = (const float*)d_in[16];
  const float* lam_sa_p  = (const float*)d_in[17];
  const float* lam_ca_p  = (const float*)d_in[18];
  const float* sa_enh_p  = (const float*)d_in[19];
  const float* ca_enh_p  = (const float*)d_in[20];
  float* out = (float*)d_out;

  const int M = in_sizes[0] / KD;            // 65536
  const int B = M / 64;                      // 1024
  const long pstride = (long)B * H6 * 2048;  // 12,582,912 elements

  char* ws = (char*)d_ws;
  float* biasw = (float*)ws;                               // 98304 B
  float* bca = (float*)(ws + 98304);                       // 2304 B
  unsigned short* wqkv   = (unsigned short*)(ws + 100864); // 221184 B
  unsigned short* wca    = (unsigned short*)(ws + 322048); // 221184 B
  unsigned short* wct_sa = (unsigned short*)(ws + 543232);
  unsigned short* wcr_sa = (unsigned short*)(ws + 616960);
  unsigned short* wct_ca = (unsigned short*)(ws + 690688);
  unsigned short* wcr_ca = (unsigned short*)(ws + 764416);
  unsigned short* wpsa   = (unsigned short*)(ws + 838144);
  unsigned short* wpca   = (unsigned short*)(ws + 911872);
  long off = 1048576;
  unsigned short* ob0 = (unsigned short*)(ws + off); off += (long)M * KD * 2;  // attn outputs
  unsigned short* ob1 = (unsigned short*)(ws + off); off += (long)M * KD * 2;
  unsigned short* ob2 = (unsigned short*)(ws + off); off += (long)M * KD * 2;
  unsigned short* ob3 = (unsigned short*)(ws + off); off += (long)M * KD * 2;
  unsigned short* caq  = (unsigned short*)(ws + off); off += pstride * 4;
  unsigned short* cak  = (unsigned short*)(ws + off); off += pstride * 4;
  unsigned short* cavT = (unsigned short*)(ws + off); off += pstride * 4;
  unsigned short* saq  = (unsigned short*)d_out;   // SA qkv staged in d_out (151 MB)
  unsigned short* sak  = saq + 2 * pstride;
  unsigned short* savT = sak + 2 * pstride;

  const float SC = 0.17677669529663687f;  // 32^-0.5

  convert_k<<<dim3(433), dim3(256), 0, stream>>>(
      sa_qkv_w, sa_ct_w, sa_cr_w, ca_q_w, ca_kv_w, ca_ct_w, ca_cr_w,
      proj_sa_w, proj_ca_w, ca_q_b, ca_kv_b,
      wqkv, wct_sa, wcr_sa, wca, wct_ca, wcr_ca, wpsa, wpca, bca);
  bias_k<<<dim3(96), dim3(256), 0, stream>>>(rpb, biasw);

  FQArgs fa;
  fa.Wc[0] = wcr_sa; fa.Wc[1] = wct_sa; fa.Wc[2] = wcr_ca; fa.Wc[3] = wct_ca;
  fa.Wq[0] = wqkv;   fa.Wq[1] = wqkv;   fa.Wq[2] = wca;    fa.Wq[3] = wca;
  fa.bias[0] = sa_qkv_b; fa.bias[1] = sa_qkv_b; fa.bias[2] = bca; fa.bias[3] = bca;
  fa.dq[0] = saq;  fa.dq[1] = saq + pstride;  fa.dq[2] = caq;  fa.dq[3] = caq + pstride;
  fa.dk[0] = sak;  fa.dk[1] = sak + pstride;  fa.dk[2] = cak;  fa.dk[3] = cak + pstride;
  fa.dv[0] = savT; fa.dv[1] = savT + pstride; fa.dv[2] = cavT; fa.dv[3] = cavT + pstride;
  fqkv_k<<<dim3(B, 4), dim3(256), 0, stream>>>(x, y, sa_enh_p, ca_enh_p, fa, SC);

  attn_k<<<dim3(B * H6 / 2), dim3(256), 0, stream>>>(saq, sak, savT, caq, cak, cavT,
                                                     biasw, lam_sa_p, lam_ca_p,
                                                     ob0, ob1, ob2, ob3, pstride);

  ProjArgs pa;
  pa.A[0] = ob0; pa.A[1] = ob1; pa.A[2] = ob2; pa.A[3] = ob3;
  pa.W[0] = wpsa; pa.W[1] = wpsa; pa.W[2] = wpca; pa.W[3] = wpca;
  pa.bias[0] = proj_sa_b; pa.bias[1] = proj_sa_b; pa.bias[2] = proj_ca_b; pa.bias[3] = proj_ca_b;
  pa.o[0] = out;                       pa.wstride[0] = 12288;
  pa.o[1] = out + (long)B * 12288;     pa.wstride[1] = 12288;
  pa.o[2] = out + (long)2 * B * 12288; pa.wstride[2] = 24576;
  pa.o[3] = out + (long)2 * B * 12288 + 12288; pa.wstride[3] = 24576;
  proj_k<<<dim3(B, 4), dim3(256), 0, stream>>>(pa);
}